// Round 8
// baseline (1637.777 us; speedup 1.0000x reference)
//
#include <hip/hip_runtime.h>
#include <cmath>
#include <stdint.h>

#define BB 32
#define TT 24
#define NN 1024
#define FF 2
#define UU 16
#define HH 32
#define TFN 31
#define NWG 256

typedef __attribute__((ext_vector_type(8))) short bf16x8;
typedef __attribute__((ext_vector_type(4))) float f32x4;
typedef unsigned short u16;
typedef unsigned int   u32;
typedef __attribute__((ext_vector_type(4))) u32 u32x4;

// Y buffer: [B][128 rows][1024] bf16, bytes XOR-swizzled within each 2048-B
// row:  byte(j,k) = j*2048 + ((2k) ^ ((j&7)<<4)).  Static row regions:
//   RU1A = rows   0..31   (ru-input cell1, even t)
//   RU1B = rows  32..63   (ru-input cell1, odd  t)
//   C1   = rows  64..79   (c-input cell1; also Ysmall at the end)
//   RU2  = rows  80..111  (ru-input cell2)
//   C2   = rows 112..127  (c-input cell2)
// Mode A (8 WGs of a batch on one XCD): plain stores -> shared L2, sc0 loads.
// Mode B: sc1 device-coherent stores/loads (MALL). Barriers ALWAYS at MALL.
#define RU1A 0
#define RU1B 32
#define C1R  64
#define RU2R 80
#define C2R  112
__device__ __align__(16) u16 g_Y[BB][128*NN];
__device__ float g_c2[BB*FF];
// MALL barrier counters, one 256-B line per batch (8 arrivals per barrier)
__device__ __align__(256) u32 g_bar[BB][64];
__device__ u32 g_xcdmask[BB];

__device__ __forceinline__ float sigmf(float x){ return 1.f/(1.f+expf(-x)); }
__device__ __forceinline__ u16 f2bf(float f){      // RNE fp32 -> bf16
  u32 u = __float_as_uint(f);
  return (u16)((u + 0x7fffu + ((u>>16)&1u)) >> 16);
}
// modeA: plain store (write-through L1 -> lands in this XCD's L2).
// modeB: agent-relaxed store (sc1: write through to MALL).
__device__ __forceinline__ void ywr(u16* Yb, int j, int n, float s, bool modeA){
  u16* p = (u16*)((char*)Yb + (j<<11) + (((n<<1)) ^ ((j&7)<<4)));
  u16 v = f2bf(s);
  if (modeA) *p = v;
  else __hip_atomic_store(p, v, __ATOMIC_RELAXED, __HIP_MEMORY_SCOPE_AGENT);
}

// ---- MALL barrier (R3/R4-proven): AGENT-relaxed RMW + relaxed polls.
// __syncthreads before the RMW drains vmcnt -> Y stores committed (L2 for
// mode A, MALL for mode B) before the arrival is visible. Last arriver skips
// polling. Backoff polling cuts MALL line pressure. Capped -> fail-fast.
__device__ __forceinline__ void bbar(u32* cnt, u32 target){
  __syncthreads();
  if (threadIdx.x == 0){
    u32 old = __hip_atomic_fetch_add(cnt, 1u, __ATOMIC_RELAXED, __HIP_MEMORY_SCOPE_AGENT);
    if (old + 1u < target){
      for (u32 it=0; it<200000u; ++it){
        if (__hip_atomic_load(cnt, __ATOMIC_RELAXED, __HIP_MEMORY_SCOPE_AGENT) >= target)
          break;
        if (it < 4) __builtin_amdgcn_s_sleep(1);
        else        __builtin_amdgcn_s_sleep(4);
      }
    }
  }
  __syncthreads();
}

// ---- stage W rows (W*2048 bytes) of swizzled Y linearly into LDS ----
// 16-B loads; mode A: sc0 (bypass L1, read shared L2). mode B: sc0 sc1 (MALL).
template<int W>
__device__ __forceinline__ void stageY(const u16* __restrict__ Yb, u16* Ys,
                                       int tid, bool modeA){
  u32x4 r[W/4];
  if (modeA){
#pragma unroll
    for (int q=0;q<W/4;q++){
      const char* src = (const char*)Yb + q*8192 + tid*16;
      asm volatile("global_load_dwordx4 %0, %1, off sc0"
                   : "=v"(r[q]) : "v"(src));
    }
  } else {
#pragma unroll
    for (int q=0;q<W/4;q++){
      const char* src = (const char*)Yb + q*8192 + tid*16;
      asm volatile("global_load_dwordx4 %0, %1, off sc0 sc1"
                   : "=v"(r[q]) : "v"(src));
    }
  }
  asm volatile("s_waitcnt vmcnt(0)" ::: "memory");
  __builtin_amdgcn_sched_barrier(0);
#pragma unroll
  for (int q=0;q<W/4;q++)
    *(u32x4*)((char*)Ys + q*8192 + tid*16) = r[q];
}

// swizzled address decomposition: (c*64 + quad*16) ^ ((m&7)<<4)
//   = ((quad ^ (m&3))<<4) + ((c ^ ((m>>2)&1))<<6)   -> base0 + ((c^cflip)<<6)
__device__ __forceinline__ void mm32(const bf16x8 (&areg)[32], const u16* Ys,
                                     int base0, int cflip, f32x4& a0, f32x4& a1){
#pragma unroll
  for (int c=0;c<32;c++){
    int off = base0 + ((c ^ cflip) << 6);
    bf16x8 b0 = *(const bf16x8*)((const char*)Ys + off);
    bf16x8 b1 = *(const bf16x8*)((const char*)Ys + off + 32768);
    a0 = __builtin_amdgcn_mfma_f32_16x16x32_bf16(areg[c], b0, a0, 0, 0, 0);
    a1 = __builtin_amdgcn_mfma_f32_16x16x32_bf16(areg[c], b1, a1, 0, 0, 0);
  }
}
__device__ __forceinline__ void mm16(const bf16x8 (&areg)[32], const u16* Ys,
                                     int base0, int cflip, f32x4& a0){
#pragma unroll
  for (int c=0;c<32;c++){
    int off = base0 + ((c ^ cflip) << 6);
    bf16x8 b0 = *(const bf16x8*)((const char*)Ys + off);
    a0 = __builtin_amdgcn_mfma_f32_16x16x32_bf16(areg[c], b0, a0, 0, 0, 0);
  }
}

// ---------------- LSTM + ff + const2 (also resets barrier/mask state) ----------------
__global__ __launch_bounds__(128)
void k_lstm(const float* __restrict__ trend, const float* __restrict__ tfeat,
            const float* __restrict__ Wih0, const float* __restrict__ Whh0,
            const float* __restrict__ bih0, const float* __restrict__ bhh0,
            const float* __restrict__ Wih1, const float* __restrict__ Whh1,
            const float* __restrict__ bih1, const float* __restrict__ bhh1,
            const float* __restrict__ ffW, const float* __restrict__ ffb,
            const float* __restrict__ gcnW) {
  __shared__ float h[HH], c[HH], g[4*HH], hs0[TT][HH], tr[HH], fe[HH];
  int b = blockIdx.x, tid = threadIdx.x;
  if (tid == 0){
    __hip_atomic_store(&g_bar[b][0],  0u, __ATOMIC_RELAXED, __HIP_MEMORY_SCOPE_AGENT);
    __hip_atomic_store(&g_xcdmask[b], 0u, __ATOMIC_RELAXED, __HIP_MEMORY_SCOPE_AGENT);
  }
  if (tid < HH) { h[tid]=0.f; c[tid]=0.f; }
  __syncthreads();
  for (int t=0;t<TT;t++) {
    float x0 = trend[(b*TT+t)*FF+0], x1 = trend[(b*TT+t)*FF+1];
    float gv = bih0[tid] + bhh0[tid] + x0*Wih0[tid*FF+0] + x1*Wih0[tid*FF+1];
#pragma unroll
    for (int k=0;k<HH;k++) gv += h[k]*Whh0[tid*HH+k];
    g[tid] = gv;
    __syncthreads();
    if (tid < HH) {
      float ii = sigmf(g[tid]), ff = sigmf(g[HH+tid]);
      float gg = tanhf(g[2*HH+tid]), oo = sigmf(g[3*HH+tid]);
      float cn = ff*c[tid] + ii*gg;
      c[tid] = cn;
      float hn = oo*tanhf(cn);
      h[tid] = hn;
      hs0[t][tid] = hn;
    }
    __syncthreads();
  }
  if (tid < HH) { h[tid]=0.f; c[tid]=0.f; }
  __syncthreads();
  for (int t=0;t<TT;t++) {
    float gv = bih1[tid] + bhh1[tid];
#pragma unroll
    for (int k=0;k<HH;k++) gv += hs0[t][k]*Wih1[tid*HH+k];
#pragma unroll
    for (int k=0;k<HH;k++) gv += h[k]*Whh1[tid*HH+k];
    g[tid] = gv;
    __syncthreads();
    if (tid < HH) {
      float ii = sigmf(g[tid]), ff = sigmf(g[HH+tid]);
      float gg = tanhf(g[2*HH+tid]), oo = sigmf(g[3*HH+tid]);
      float cn = ff*c[tid] + ii*gg;
      c[tid] = cn;
      h[tid] = oo*tanhf(cn);
    }
    __syncthreads();
  }
  if (tid < HH) {
    tr[tid] = h[tid];
    float fv = ffb[tid];
#pragma unroll
    for (int j=0;j<TFN;j++) fv += tfeat[b*TFN+j]*ffW[tid*TFN+j];
    fe[tid] = fmaxf(fv, 0.f);
  }
  __syncthreads();
  if (tid < FF) {
    float s = 0.f;
#pragma unroll
    for (int j=0;j<HH;j++) s += tr[j]*gcnW[tid*80+16+j];
#pragma unroll
    for (int j=0;j<HH;j++) s += fe[j]*gcnW[tid*80+48+j];
    g_c2[b*FF+tid] = s;
  }
}

// ---------------- persistent cooperative kernel: whole recurrence ----------------
struct KP {
  const float *recent, *A;
  const float *g1rW,*g1rb,*g1uW,*g1ub,*g1cW,*g1cb;
  const float *g2rW,*g2rb,*g2uW,*g2ub,*g2cW,*g2cb;
  const float *gcnW,*gcnb;
  float *out;
};

__global__ __launch_bounds__(512, 2)
void k_main(KP p){
  __shared__ __align__(16) u16 Ys[32*NN];   // 64 KB swizzled Y tile
  __shared__ float Ps [128][33];
  __shared__ float h1s[128][17];
  __shared__ float h2s[128][17];
  __shared__ float us_[128][17];
  __shared__ float rhs[128][17];

  const int wg = blockIdx.x;
  // XCD-grouped work mapping (round-robin dispatch: WGs {x, x+8, ...} share
  // XCD x). XCD x owns batches x*4 .. x*4+3, 8 row-chunks each.
  const int b = (wg & 7)*4 + (wg >> 6);
  const int i0 = ((wg >> 3) & 7) << 7;
  const int tid = threadIdx.x;
  const int v = tid >> 6, lane = tid & 63, m = lane & 15, quad = lane >> 4;
  const int rloc = v << 4;
  const int row = tid >> 2, jj = tid & 3;   // epilogue mapping: 4 thr/row
  const int n = i0 + row;
  const int base0 = m*2048 + ((quad ^ (m & 3)) << 4);
  const int cflip = (m >> 2) & 1;
  u32* bar = &g_bar[b][0];
  u16* Yb  = &g_Y[b][0];

  // publish this WG's XCD id; the used return value forces MALL visibility
  // BEFORE this WG's first barrier arrival.
  if (tid == 0){
    u32 xcc;
    asm volatile("s_getreg_b32 %0, hwreg(HW_REG_XCC_ID)" : "=s"(xcc));
    u32 oldm = __hip_atomic_fetch_or(&g_xcdmask[b], 1u << (xcc & 31),
                                     __ATOMIC_RELAXED, __HIP_MEMORY_SCOPE_AGENT);
    asm volatile("" :: "v"(oldm));
  }

  // ---- prologue: park A rows in registers (bf16), read fp32 A once ----
  bf16x8 areg[32];
  {
    const float* Ab = p.A + ((size_t)(b*NN + i0 + rloc + m))*NN + quad*8;
#pragma unroll
    for (int c=0;c<32;c++){
      float4 f0 = *(const float4*)(Ab + c*32);
      float4 f1 = *(const float4*)(Ab + c*32 + 4);
      bf16x8 tv;
      tv[0]=(short)f2bf(f0.x); tv[1]=(short)f2bf(f0.y);
      tv[2]=(short)f2bf(f0.z); tv[3]=(short)f2bf(f0.w);
      tv[4]=(short)f2bf(f1.x); tv[5]=(short)f2bf(f1.y);
      tv[6]=(short)f2bf(f1.z); tv[7]=(short)f2bf(f1.w);
      areg[c] = tv;
    }
  }

  // zero hidden state
#pragma unroll
  for (int q=0;q<4;q++){ h1s[row][jj*4+q]=0.f; h2s[row][jj*4+q]=0.f; }

  // ---- Yru1(t=0) -> RU1A: mode unknown yet -> device-coherent writes ----
  {
    const float* xr = p.recent + (((size_t)b*TT)*NN + n)*FF;
    float x0 = xr[0], x1 = xr[1];
    u16* Yr = Yb + RU1A*NN;
#pragma unroll
    for (int m2=0;m2<8;m2++){
      int j = jj*8 + m2;
      const float* W = (j<16) ? (p.g1rW + j*18) : (p.g1uW + (j-16)*18);
      ywr(Yr, j, n, x0*W[0] + x1*W[1], false);
    }
  }
  u32 gen = 0;
  bbar(bar, (++gen)*8);

  // group placement decision (uniform across the 8 WGs of this batch)
  const u32 mk = __hip_atomic_load(&g_xcdmask[b], __ATOMIC_RELAXED,
                                   __HIP_MEMORY_SCOPE_AGENT);
  const bool modeA = (__popc(mk) == 1);

  for (int t=0;t<TT;t++){
    // ======== sweep 1: r,u cell1 (w32, from RU1[t&1]); epi -> C1 ========
    stageY<32>(Yb + ((t&1) ? RU1B : RU1A)*NN, Ys, tid, modeA);
    __syncthreads();
    {
      f32x4 a0={0.f,0.f,0.f,0.f}, a1={0.f,0.f,0.f,0.f};
      mm32(areg, Ys, base0, cflip, a0, a1);
#pragma unroll
      for (int r=0;r<4;r++){
        Ps[rloc + quad*4 + r][m]    = a0[r];
        Ps[rloc + quad*4 + r][16+m] = a1[r];
      }
    }
    __syncthreads();
#pragma unroll
    for (int q=0;q<4;q++){
      int j = jj*4+q;
      float rv = sigmf(Ps[row][j]    + p.g1rb[j]);
      float uv = sigmf(Ps[row][16+j] + p.g1ub[j]);
      us_[row][j] = uv;
      rhs[row][j] = rv * h1s[row][j];
    }
    __syncthreads();
    {
      const float* xr = p.recent + (((size_t)b*TT + t)*NN + n)*FF;
      float x0 = xr[0], x1 = xr[1];
      u16* Yc = Yb + C1R*NN;
#pragma unroll
      for (int q=0;q<4;q++){
        int j = jj*4+q;
        const float* W = p.g1cW + j*18;
        float s = fmaf(x0, W[0], x1*W[1]);
#pragma unroll
        for (int f=0;f<16;f++) s = fmaf(rhs[row][f], W[2+f], s);
        ywr(Yc, j, n, s, modeA);
      }
    }
    bbar(bar, (++gen)*8);   // B1

    // ======== sweep 2: c cell1 (w16, C1) -> h1; epi -> RU2 + RU1[t+1] ========
    stageY<16>(Yb + C1R*NN, Ys, tid, modeA);
    __syncthreads();
    {
      f32x4 a0={0.f,0.f,0.f,0.f};
      mm16(areg, Ys, base0, cflip, a0);
#pragma unroll
      for (int r=0;r<4;r++) Ps[rloc + quad*4 + r][m] = a0[r];
    }
    __syncthreads();
#pragma unroll
    for (int q=0;q<4;q++){
      int j = jj*4+q;
      float cv = tanhf(Ps[row][j] + p.g1cb[j]);
      float uv = us_[row][j];
      h1s[row][j] = uv*h1s[row][j] + (1.f-uv)*cv;
    }
    __syncthreads();
    {
      u16* Yr2 = Yb + RU2R*NN;
#pragma unroll
      for (int m2=0;m2<8;m2++){
        int j = jj*8 + m2;
        const float* W = (j<16) ? (p.g2rW + j*32) : (p.g2uW + (j-16)*32);
        float s = 0.f;
#pragma unroll
        for (int f=0;f<16;f++) s = fmaf(h1s[row][f], W[f],    s);
#pragma unroll
        for (int f=0;f<16;f++) s = fmaf(h2s[row][f], W[16+f], s);
        ywr(Yr2, j, n, s, modeA);
      }
      if (t < TT-1){
        const float* xr = p.recent + (((size_t)b*TT + t + 1)*NN + n)*FF;
        float x0 = xr[0], x1 = xr[1];
        u16* Yr1 = Yb + (((t+1)&1) ? RU1B : RU1A)*NN;
#pragma unroll
        for (int m2=0;m2<8;m2++){
          int j = jj*8 + m2;
          const float* W = (j<16) ? (p.g1rW + j*18) : (p.g1uW + (j-16)*18);
          float s = fmaf(x0, W[0], x1*W[1]);
#pragma unroll
          for (int f=0;f<16;f++) s = fmaf(h1s[row][f], W[2+f], s);
          ywr(Yr1, j, n, s, modeA);
        }
      }
    }
    bbar(bar, (++gen)*8);   // B2

    // ======== sweep 3: r,u cell2 (w32, RU2); epi -> C2 ========
    stageY<32>(Yb + RU2R*NN, Ys, tid, modeA);
    __syncthreads();
    {
      f32x4 a0={0.f,0.f,0.f,0.f}, a1={0.f,0.f,0.f,0.f};
      mm32(areg, Ys, base0, cflip, a0, a1);
#pragma unroll
      for (int r=0;r<4;r++){
        Ps[rloc + quad*4 + r][m]    = a0[r];
        Ps[rloc + quad*4 + r][16+m] = a1[r];
      }
    }
    __syncthreads();
#pragma unroll
    for (int q=0;q<4;q++){
      int j = jj*4+q;
      float rv = sigmf(Ps[row][j]    + p.g2rb[j]);
      float uv = sigmf(Ps[row][16+j] + p.g2ub[j]);
      us_[row][j] = uv;
      rhs[row][j] = rv * h2s[row][j];
    }
    __syncthreads();
    {
      u16* Yc2 = Yb + C2R*NN;
#pragma unroll
      for (int q=0;q<4;q++){
        int j = jj*4+q;
        const float* W = p.g2cW + j*32;
        float s = 0.f;
#pragma unroll
        for (int f=0;f<16;f++) s = fmaf(h1s[row][f], W[f],    s);
#pragma unroll
        for (int f=0;f<16;f++) s = fmaf(rhs[row][f], W[16+f], s);
        ywr(Yc2, j, n, s, modeA);
      }
    }
    bbar(bar, (++gen)*8);   // B3

    // ======== sweep 4: c cell2 (w16, C2) -> h2; NO barrier after ========
    stageY<16>(Yb + C2R*NN, Ys, tid, modeA);
    __syncthreads();
    {
      f32x4 a0={0.f,0.f,0.f,0.f};
      mm16(areg, Ys, base0, cflip, a0);
#pragma unroll
      for (int r=0;r<4;r++) Ps[rloc + quad*4 + r][m] = a0[r];
    }
    __syncthreads();
#pragma unroll
    for (int q=0;q<4;q++){
      int j = jj*4+q;
      float cv = tanhf(Ps[row][j] + p.g2cb[j]);
      float uv = us_[row][j];
      h2s[row][j] = uv*h2s[row][j] + (1.f-uv)*cv;
    }
    __syncthreads();
    if (t == TT-1){
      // Ysmall -> C1 region (rows 0..15; only rows 0,1 nonzero)
      u16* Yc = Yb + C1R*NN;
#pragma unroll
      for (int q=0;q<4;q++){
        int j = jj*4+q;
        float s = 0.f;
        if (j < FF){
          s = g_c2[b*FF + j];
#pragma unroll
          for (int f=0;f<16;f++) s = fmaf(h2s[row][f], p.gcnW[j*80+f], s);
        }
        ywr(Yc, j, n, s, modeA);
      }
      bbar(bar, (++gen)*8);   // B4 (final only)
    }
  }

  // ======== final: out = tanh(A @ Ysmall + gcnb) ========
  stageY<16>(Yb + C1R*NN, Ys, tid, modeA);
  __syncthreads();
  {
    f32x4 a0={0.f,0.f,0.f,0.f};
    mm16(areg, Ys, base0, cflip, a0);
    if (m < FF){
      float bb = p.gcnb[m];
#pragma unroll
      for (int r=0;r<4;r++){
        int nn = i0 + rloc + quad*4 + r;
        p.out[((size_t)b*NN + nn)*FF + m] = tanhf(a0[r] + bb);
      }
    }
  }
}

extern "C" void kernel_launch(void* const* d_in, const int* in_sizes, int n_in,
                              void* d_out, int out_size, void* d_ws, size_t ws_size,
                              hipStream_t stream) {
  (void)in_sizes; (void)n_in; (void)d_ws; (void)ws_size; (void)out_size;
  const float* recent = (const float*)d_in[0];
  const float* trend  = (const float*)d_in[1];
  const float* A      = (const float*)d_in[2];
  const float* tfeat  = (const float*)d_in[3];
  const float* g1rW = (const float*)d_in[4];  const float* g1rb = (const float*)d_in[5];
  const float* g1uW = (const float*)d_in[6];  const float* g1ub = (const float*)d_in[7];
  const float* g1cW = (const float*)d_in[8];  const float* g1cb = (const float*)d_in[9];
  const float* g2rW = (const float*)d_in[10]; const float* g2rb = (const float*)d_in[11];
  const float* g2uW = (const float*)d_in[12]; const float* g2ub = (const float*)d_in[13];
  const float* g2cW = (const float*)d_in[14]; const float* g2cb = (const float*)d_in[15];
  const float* Wih0 = (const float*)d_in[16]; const float* Whh0 = (const float*)d_in[17];
  const float* bih0 = (const float*)d_in[18]; const float* bhh0 = (const float*)d_in[19];
  const float* Wih1 = (const float*)d_in[20]; const float* Whh1 = (const float*)d_in[21];
  const float* bih1 = (const float*)d_in[22]; const float* bhh1 = (const float*)d_in[23];
  const float* ffW  = (const float*)d_in[24]; const float* ffb  = (const float*)d_in[25];
  const float* gcnW = (const float*)d_in[26]; const float* gcnb = (const float*)d_in[27];
  float* out = (float*)d_out;

  // resets barrier/mask state + computes g_c2; ordered before k_main
  k_lstm<<<BB, 128, 0, stream>>>(trend, tfeat, Wih0, Whh0, bih0, bhh0,
                                 Wih1, Whh1, bih1, bhh1, ffW, ffb, gcnW);

  KP kp;
  kp.recent = recent; kp.A = A;
  kp.g1rW=g1rW; kp.g1rb=g1rb; kp.g1uW=g1uW; kp.g1ub=g1ub; kp.g1cW=g1cW; kp.g1cb=g1cb;
  kp.g2rW=g2rW; kp.g2rb=g2rb; kp.g2uW=g2uW; kp.g2ub=g2ub; kp.g2cW=g2cW; kp.g2cb=g2cb;
  kp.gcnW=gcnW; kp.gcnb=gcnb; kp.out=out;
  void* args[] = { (void*)&kp };
  hipLaunchCooperativeKernel((const void*)k_main, dim3(NWG), dim3(512), args, 0, stream);
}